// Round 5
// baseline (27.022 us; speedup 1.0000x reference)
//
#include <hip/hip_runtime.h>
#include <math.h>

#define N 512
#define C 256          // distinct label-diff classes per row (labels repeat)
#define D 128

// ---------------- KA: all-pairs logits via LDS-staged 32x32 tiles + ws init ----------------
__global__ __launch_bounds__(256) void ka_logits(const float* __restrict__ feat,
                                                 float* __restrict__ lg,
                                                 double* __restrict__ acc,
                                                 unsigned* __restrict__ cnt) {
    const int tid = threadIdx.x;
    if (blockIdx.x == 0 && tid == 0) { *acc = 0.0; *cnt = 0u; }   // reset every call (graph-safe)

    const int row0 = (blockIdx.x >> 4) << 5;
    const int col0 = (blockIdx.x & 15) << 5;

    __shared__ float4 As[32][32];   // [row][swizzled q]
    __shared__ float4 Bs[32][32];

    const float4* f4 = (const float4*)feat;   // [512][32]
    {
        const int r = tid >> 5, c4 = tid & 31;
#pragma unroll
        for (int p = 0; p < 4; ++p) {
            const int rr = r + p * 8;
            const int sc = c4 ^ ((rr >> 1) & 7);
            As[rr][sc] = f4[(size_t)(row0 + rr) * 32 + c4];
            Bs[rr][sc] = f4[(size_t)(col0 + rr) * 32 + c4];
        }
    }
    __syncthreads();

    const int ty = tid >> 4, tx = tid & 15;
    const int r0 = 2 * ty, r1 = 2 * ty + 1;
    const int c0 = 2 * tx, c1 = 2 * tx + 1;
    const int sa = ty & 7, sb = tx & 7;

    float s00 = 0.f, s01 = 0.f, s10 = 0.f, s11 = 0.f;
#pragma unroll 8
    for (int q = 0; q < 32; ++q) {
        float4 a0 = As[r0][q ^ sa];
        float4 a1 = As[r1][q ^ sa];
        float4 b0 = Bs[c0][q ^ sb];
        float4 b1 = Bs[c1][q ^ sb];
        float t;
        t = a0.x - b0.x; s00 = fmaf(t, t, s00);
        t = a0.y - b0.y; s00 = fmaf(t, t, s00);
        t = a0.z - b0.z; s00 = fmaf(t, t, s00);
        t = a0.w - b0.w; s00 = fmaf(t, t, s00);
        t = a0.x - b1.x; s01 = fmaf(t, t, s01);
        t = a0.y - b1.y; s01 = fmaf(t, t, s01);
        t = a0.z - b1.z; s01 = fmaf(t, t, s01);
        t = a0.w - b1.w; s01 = fmaf(t, t, s01);
        t = a1.x - b0.x; s10 = fmaf(t, t, s10);
        t = a1.y - b0.y; s10 = fmaf(t, t, s10);
        t = a1.z - b0.z; s10 = fmaf(t, t, s10);
        t = a1.w - b0.w; s10 = fmaf(t, t, s10);
        t = a1.x - b1.x; s11 = fmaf(t, t, s11);
        t = a1.y - b1.y; s11 = fmaf(t, t, s11);
        t = a1.z - b1.z; s11 = fmaf(t, t, s11);
        t = a1.w - b1.w; s11 = fmaf(t, t, s11);
    }
    // safe_l2: identical rows give s == 0 exactly -> logit 0 (diagonal)
    float l00 = (s00 > 0.f) ? -0.5f * sqrtf(s00) : 0.f;
    float l01 = (s01 > 0.f) ? -0.5f * sqrtf(s01) : 0.f;
    float l10 = (s10 > 0.f) ? -0.5f * sqrtf(s10) : 0.f;
    float l11 = (s11 > 0.f) ? -0.5f * sqrtf(s11) : 0.f;

    *(float2*)(lg + (size_t)(row0 + r0) * N + col0 + c0) = make_float2(l00, l01);
    *(float2*)(lg + (size_t)(row0 + r1) * N + col0 + c0) = make_float2(l10, l11);
}

// ---------------- KB: fused per-row max/exp/class/denoms/loss + last-block final ----------------
__global__ __launch_bounds__(256) void kb_row(const float* __restrict__ lg,
                                              const float* __restrict__ labels,
                                              double* __restrict__ acc,
                                              unsigned* __restrict__ cnt,
                                              float* __restrict__ out) {
    const int i = blockIdx.x;
    const int c = threadIdx.x;

    __shared__ alignas(16) float sld[C];
    __shared__ alignas(16) float sev[C];
    __shared__ float redm[4], reds[4], redl[4];
    __shared__ float lci;

    // coalesced row read
    const float la = lg[(size_t)i * N + c];
    const float lb = lg[(size_t)i * N + c + 256];

    // row max over j != i (lg[i][i] == 0 excluded)
    float m = -1e30f;
    if (c != i) m = la;
    if (c + 256 != i) m = fmaxf(m, lb);
#pragma unroll
    for (int off = 32; off > 0; off >>= 1) m = fmaxf(m, __shfl_xor(m, off, 64));
    if ((c & 63) == 0) redm[c >> 6] = m;
    __syncthreads();
    m = fmaxf(fmaxf(redm[0], redm[1]), fmaxf(redm[2], redm[3]));

    // exp values; diagonal forced to 0 drops it from every denominator
    const float ea = (c == i) ? 0.f : __expf(la - m);
    const float eb = (c + 256 == i) ? 0.f : __expf(lb - m);
    sev[c] = ea + eb;

    // label diff per class (bitwise identical to reference f32 math)
    const float2 lc2 = ((const float2*)labels)[c];
    const float2 li2 = ((const float2*)labels)[i & 255];
    const float ldk = fabsf(li2.x - lc2.x) + fabsf(li2.y - lc2.y);
    sld[c] = ldk;

    // rowsum = sum_{k != i}(lg_k - m) = (sum_k lg_k) - 511*m   (lg_i == 0)
    float s = la + lb;
#pragma unroll
    for (int off = 32; off > 0; off >>= 1) s += __shfl_xor(s, off, 64);
    if ((c & 63) == 0) reds[c >> 6] = s;
    __syncthreads();                    // also publishes sld/sev
    const float rowsum = (reds[0] + reds[1] + reds[2] + reds[3]) - 511.f * m;

    // denominator for class c: wave-uniform LDS float4 broadcasts, conflict-free
    const float4* a4 = (const float4*)sld;
    const float4* b4 = (const float4*)sev;
    float d0 = 0.f, d1 = 0.f, d2 = 0.f, d3 = 0.f;
#pragma unroll 8
    for (int q = 0; q < C / 4; ++q) {
        float4 a = a4[q];
        float4 b = b4[q];
        d0 += (a.x >= ldk) ? b.x : 0.f;
        d1 += (a.y >= ldk) ? b.y : 0.f;
        d2 += (a.z >= ldk) ? b.z : 0.f;
        d3 += (a.w >= ldk) ? b.w : 0.f;
    }
    const float lden = __logf((d0 + d1) + (d2 + d3));

    // rowout = rowsum - (2*sum_c log den_c - log den_{class(i)})
    if (c == (i & 255)) lci = lden;     // class(i): ld == 0 -> den == total ev sum
    float t = lden;
#pragma unroll
    for (int off = 32; off > 0; off >>= 1) t += __shfl_xor(t, off, 64);
    if ((c & 63) == 0) redl[c >> 6] = t;
    __syncthreads();
    if (c == 0) {
        const float tot = redl[0] + redl[1] + redl[2] + redl[3];
        const float part = rowsum - (2.f * tot - lci);
        atomicAdd(acc, (double)part);
        __threadfence();
        const unsigned prev = atomicAdd(cnt, 1u);
        if (prev == (unsigned)(N - 1)) {            // last block finishing
            const double total = atomicAdd(acc, 0.0);   // coherent device-scope read
            out[0] = (float)(-total / ((double)N * (double)(N - 1)));
        }
    }
}

extern "C" void kernel_launch(void* const* d_in, const int* in_sizes, int n_in,
                              void* d_out, int out_size, void* d_ws, size_t ws_size,
                              hipStream_t stream) {
    const float* feat   = (const float*)d_in[0];   // [512,128] f32
    const float* labels = (const float*)d_in[1];   // [256,2]  f32
    float* out = (float*)d_out;

    float*    lg  = (float*)d_ws;                          // N*N f32 (1 MB)
    double*   acc = (double*)((char*)d_ws + (size_t)N * N * sizeof(float));
    unsigned* cnt = (unsigned*)(acc + 1);

    ka_logits<<<256, 256, 0, stream>>>(feat, lg, acc, cnt);
    kb_row  <<<N,   256, 0, stream>>>(lg, labels, acc, cnt, out);
}